// Round 2
// baseline (217.986 us; speedup 1.0000x reference)
//
#include <hip/hip_runtime.h>

// ---------------------------------------------------------------------------
// Threefry2x32 (JAX-compatible), usable at compile time (constexpr) and runtime
// PRNG layer assumes jax_threefry_partitionable=True (JAX >= 0.4.30 default):
//   fold_in(key,d)        = threefry(key,(0,d))            (both modes)
//   split(key,n)[m]       = threefry(key,(0,m))  full pair (foldlike)
//   random_bits(32)[i]    = v0 ^ v1 of threefry(key,(0,i)) (counter mode)
// ---------------------------------------------------------------------------
struct KP { unsigned a, b; };

__host__ __device__ constexpr unsigned rotl32(unsigned x, int d) {
  return (x << d) | (x >> (32 - d));
}

__host__ __device__ constexpr KP tf2x32(unsigned k0, unsigned k1, unsigned x0, unsigned x1) {
  unsigned k2 = k0 ^ k1 ^ 0x1BD11BDAu;
  unsigned v0 = x0 + k0;
  unsigned v1 = x1 + k1;
  const int R[5][4] = {{13,15,26,6},{17,29,16,24},{13,15,26,6},{17,29,16,24},{13,15,26,6}};
  const unsigned KI[5][2] = {{k1, k2 + 1u},{k2, k0 + 2u},{k0, k1 + 3u},{k1, k2 + 4u},{k2, k0 + 5u}};
  for (int g = 0; g < 5; ++g) {
    for (int r = 0; r < 4; ++r) {
      v0 += v1;
      v1 = rotl32(v1, R[g][r]);
      v1 ^= v0;
    }
    v0 += KI[g][0];
    v1 += KI[g][1];
  }
  return KP{v0, v1};
}

// Compile-time key schedule: root key (0,42); per-level fold_in + foldlike
// split(5); corner key fold_in(1000).
struct AllKeys {
  unsigned lk[9][5][2];   // [level][stream: centers,top,left,right,bottom][k0,k1]
  unsigned ck[2];         // corner key
};

__host__ __device__ constexpr AllKeys make_keys() {
  AllKeys K{};
  for (int l = 0; l < 9; ++l) {
    KP base = tf2x32(0u, 42u, 0u, (unsigned)l);          // fold_in(key, level)
    for (int m = 0; m < 5; ++m) {                        // foldlike split
      KP s = tf2x32(base.a, base.b, 0u, (unsigned)m);
      K.lk[l][m][0] = s.a;
      K.lk[l][m][1] = s.b;
    }
  }
  KP ck = tf2x32(0u, 42u, 0u, 1000u);                    // fold_in(key, 1000)
  K.ck[0] = ck.a;
  K.ck[1] = ck.b;
  return K;
}

constexpr AllKeys KEYS = make_keys();

#define NG 513

// partitionable random_bits(32): element i = v0 ^ v1 of cipher(key, (0, i))
__device__ inline unsigned rbits(unsigned k0, unsigned k1, unsigned i) {
  KP o = tf2x32(k0, k1, 0u, i);
  return o.a ^ o.b;
}

__device__ inline float bits_to_u(unsigned b, float r) {
  float u = __uint_as_float((b >> 9) | 0x3f800000u) - 1.0f;   // [0,1)
  return fmaxf(-r, u * (2.0f * r) - r);                       // uniform(-r, r)
}

__device__ inline float draw_u(const unsigned* kk, unsigned i, float r) {
  return bits_to_u(rbits(kk[0], kk[1], i), r);
}

// recompute center of cell (a,b) at given level (reads only coarser-level hm)
__device__ inline float cell_center(const float* hm, int level, int g, int L,
                                    int a, int b, float r) {
  int lo_i = a * L, hi_i = lo_i + L, lo_j = b * L, hi_j = lo_j + L;
  float nw = hm[lo_i * NG + lo_j], ne = hm[lo_i * NG + hi_j];
  float sw = hm[hi_i * NG + lo_j], se = hm[hi_i * NG + hi_j];
  return (nw + ne + sw + se) * 0.25f +
         draw_u(KEYS.lk[level][0], (unsigned)(a * g + b), r);
}

__device__ inline void do_cell(float* hm, int level, int i, int j) {
  int g = 1 << level;
  int L = 512 >> level;
  int h = L >> 1;
  float r = 1.0f / (float)(level + 1);
  int lo_i = i * L, hi_i = lo_i + L, mi_i = lo_i + h;
  int lo_j = j * L, hi_j = lo_j + L, mi_j = lo_j + h;
  float nw = hm[lo_i * NG + lo_j], ne = hm[lo_i * NG + hi_j];
  float sw = hm[hi_i * NG + lo_j], se = hm[hi_i * NG + hi_j];
  unsigned m = (unsigned)(i * g + j);

  float c = (nw + ne + sw + se) * 0.25f + draw_u(KEYS.lk[level][0], m, r);
  hm[mi_i * NG + mi_j] = c;

  // right edge midpoint (temp_r: own center, wraps to column 0 on last column)
  float tr = (j < g - 1) ? c : cell_center(hm, level, g, L, i, 0, r);
  float right = (c + ne + se + tr) * 0.25f + draw_u(KEYS.lk[level][3], m, r);
  hm[mi_i * NG + hi_j] = right;

  // bottom edge midpoint (temp_b: own center, wraps to row 0 on last row)
  float tb = (i < g - 1) ? c : cell_center(hm, level, g, L, 0, j, r);
  float bottom = (c + sw + se + tb) * 0.25f + draw_u(KEYS.lk[level][4], m, r);
  hm[hi_i * NG + mi_j] = bottom;

  if (i == 0) {  // top row midpoints
    float cg1 = (g == 1) ? c : cell_center(hm, level, g, L, g - 1, j, r);
    float top = (c + hm[lo_j] + hm[hi_j] + cg1) * 0.25f +
                draw_u(KEYS.lk[level][1], (unsigned)j, r);
    hm[mi_j] = top;
  }
  if (j == 0) {  // left column midpoints
    float cg1 = (g == 1) ? c : cell_center(hm, level, g, L, i, g - 1, r);
    float left = (c + hm[lo_i * NG] + hm[hi_i * NG] + cg1) * 0.25f +
                 draw_u(KEYS.lk[level][2], (unsigned)i, r);
    hm[mi_i * NG] = left;
  }
}

// corners + levels 0..5 in one block (<=1024 cells per level)
__global__ void k_ds_small(float* hm, unsigned* mmx) {
  int tid = threadIdx.x;
  if (tid == 0) {
#pragma unroll
    for (int q = 0; q < 4; ++q) {
      float v = bits_to_u(rbits(KEYS.ck[0], KEYS.ck[1], (unsigned)q), 1.0f);
      int y = (q >> 1) ? 512 : 0;
      int x = (q & 1) ? 512 : 0;
      hm[y * NG + x] = v;
    }
    mmx[0] = 0xFFFFFFFFu;  // min slot (atomicMin target)
    mmx[1] = 0u;           // max slot (atomicMax target)
  }
  __syncthreads();
  for (int lvl = 0; lvl <= 5; ++lvl) {
    int g = 1 << lvl;
    if (tid < g * g) do_cell(hm, lvl, tid >> lvl, tid & (g - 1));
    __syncthreads();
  }
}

__global__ void k_level(float* hm, int level) {
  int g = 1 << level;
  int gt = blockIdx.x * blockDim.x + threadIdx.x;
  do_cell(hm, level, gt >> level, gt & (g - 1));
}

__device__ inline unsigned enc_f(float f) {
  unsigned u = __float_as_uint(f);
  return (u & 0x80000000u) ? ~u : (u | 0x80000000u);
}
__device__ inline float dec_f(unsigned e) {
  unsigned u = (e & 0x80000000u) ? (e & 0x7FFFFFFFu) : ~e;
  return __uint_as_float(u);
}

__global__ void k_minmax(const float* hm, unsigned* mmx) {
  int gtid = blockIdx.x * blockDim.x + threadIdx.x;
  int nthreads = gridDim.x * blockDim.x;
  float mn = 3.4e38f, mx = -3.4e38f;
  for (int idx = gtid; idx < NG * NG; idx += nthreads) {
    float v = hm[idx];
    mn = fminf(mn, v);
    mx = fmaxf(mx, v);
  }
#pragma unroll
  for (int off = 32; off >= 1; off >>= 1) {
    mn = fminf(mn, __shfl_down(mn, off, 64));
    mx = fmaxf(mx, __shfl_down(mx, off, 64));
  }
  if ((threadIdx.x & 63) == 0) {
    atomicMin(&mmx[0], enc_f(mn));
    atomicMax(&mmx[1], enc_f(mx));
  }
}

// rn[512x512] = 0.5 * resize_bilinear_antialias(normalized hm, 513->512)
// exact two-tap triangle weights: kernel_scale = 513/512, sample o + (2o+1)/1024
__global__ void k_noise(const float* hm, const unsigned* mmx, float* rn) {
  int o = blockIdx.x * blockDim.x + threadIdx.x;  // 0..262143
  int oy = o >> 9, ox = o & 511;
  const float csc = 512.0f / 513.0f;
  float dx = (float)(2 * ox + 1) * (1.0f / 1024.0f);
  float wx0 = 1.0f - dx * csc;
  float wx1 = 1.0f - (1.0f - dx) * csc;
  float sx = wx0 + wx1;
  wx0 /= sx; wx1 /= sx;
  float dy = (float)(2 * oy + 1) * (1.0f / 1024.0f);
  float wy0 = 1.0f - dy * csc;
  float wy1 = 1.0f - (1.0f - dy) * csc;
  float sy = wy0 + wy1;
  wy0 /= sy; wy1 /= sy;
  const float* r0 = hm + oy * NG + ox;
  float v = wy0 * (wx0 * r0[0] + wx1 * r0[1]) + wy1 * (wx0 * r0[NG] + wx1 * r0[NG + 1]);
  float mn = dec_f(mmx[0]), mx = dec_f(mmx[1]);
  rn[o] = 0.5f * ((v - mn) / (mx - mn));
}

__global__ void k_apply(const float4* __restrict__ img, const float* __restrict__ rn,
                        float4* __restrict__ out) {
  int t = blockIdx.x * blockDim.x + threadIdx.x;       // float4 index
  int pos4 = t & ((512 * 512 / 4) - 1);                // within-plane float4 idx
  float4 a = img[t];
  float4 n = reinterpret_cast<const float4*>(rn)[pos4];
  float4 o;
  o.x = fminf(fmaxf(a.x * (1.0f - n.x) + n.x, 0.0f), 1.0f);
  o.y = fminf(fmaxf(a.y * (1.0f - n.y) + n.y, 0.0f), 1.0f);
  o.z = fminf(fmaxf(a.z * (1.0f - n.z) + n.z, 0.0f), 1.0f);
  o.w = fminf(fmaxf(a.w * (1.0f - n.w) + n.w, 0.0f), 1.0f);
  out[t] = o;
}

// fallback if ws is too small for the rn buffer: compute noise inline per element
__global__ void k_apply_direct(const float* __restrict__ img, const float* __restrict__ hm,
                               const unsigned* __restrict__ mmx, float* __restrict__ out) {
  int t = blockIdx.x * blockDim.x + threadIdx.x;
  int pos = t & (512 * 512 - 1);
  int oy = pos >> 9, ox = pos & 511;
  const float csc = 512.0f / 513.0f;
  float dx = (float)(2 * ox + 1) * (1.0f / 1024.0f);
  float wx0 = 1.0f - dx * csc;
  float wx1 = 1.0f - (1.0f - dx) * csc;
  float sx = wx0 + wx1;
  wx0 /= sx; wx1 /= sx;
  float dy = (float)(2 * oy + 1) * (1.0f / 1024.0f);
  float wy0 = 1.0f - dy * csc;
  float wy1 = 1.0f - (1.0f - dy) * csc;
  float sy = wy0 + wy1;
  wy0 /= sy; wy1 /= sy;
  const float* r0 = hm + oy * NG + ox;
  float v = wy0 * (wx0 * r0[0] + wx1 * r0[1]) + wy1 * (wx0 * r0[NG] + wx1 * r0[NG + 1]);
  float mn = dec_f(mmx[0]), mx = dec_f(mmx[1]);
  float rnv = 0.5f * ((v - mn) / (mx - mn));
  float a = img[t];
  out[t] = fminf(fmaxf(a * (1.0f - rnv) + rnv, 0.0f), 1.0f);
}

extern "C" void kernel_launch(void* const* d_in, const int* in_sizes, int n_in,
                              void* d_out, int out_size, void* d_ws, size_t ws_size,
                              hipStream_t stream) {
  const float* img = (const float*)d_in[0];
  float* out = (float*)d_out;
  unsigned char* ws = (unsigned char*)d_ws;

  const size_t RN_BYTES = 512 * 512 * sizeof(float);
  const size_t HM_BYTES = NG * NG * sizeof(float);
  const size_t need_full = 16 + RN_BYTES + HM_BYTES;

  unsigned* mmx = (unsigned*)ws;
  bool use_rn = (ws_size >= need_full);
  float* rn = (float*)(ws + 16);
  float* hm = use_rn ? (float*)(ws + 16 + RN_BYTES) : (float*)(ws + 16);

  // diamond-square: corners + levels 0..5 in one block, then levels 6..8
  hipLaunchKernelGGL(k_ds_small, dim3(1), dim3(1024), 0, stream, hm, mmx);
  hipLaunchKernelGGL(k_level, dim3(16), dim3(256), 0, stream, hm, 6);
  hipLaunchKernelGGL(k_level, dim3(64), dim3(256), 0, stream, hm, 7);
  hipLaunchKernelGGL(k_level, dim3(256), dim3(256), 0, stream, hm, 8);
  // global min/max
  hipLaunchKernelGGL(k_minmax, dim3(64), dim3(256), 0, stream, hm, mmx);

  const int total = 32 * 3 * 512 * 512;
  if (use_rn) {
    hipLaunchKernelGGL(k_noise, dim3(512 * 512 / 256), dim3(256), 0, stream, hm, mmx, rn);
    hipLaunchKernelGGL(k_apply, dim3(total / 4 / 256), dim3(256), 0, stream,
                       (const float4*)img, rn, (float4*)out);
  } else {
    hipLaunchKernelGGL(k_apply_direct, dim3(total / 256), dim3(256), 0, stream,
                       img, hm, mmx, out);
  }
}